// Round 8
// baseline (4381.025 us; speedup 1.0000x reference)
//
#include <hip/hip_runtime.h>
#include <cstdint>
#include <cstddef>

#define N_NODES 100000
#define N_EDGES 1200000
#define ASIZE 256
#define HSIZE 64
#define NTYPES 4
#define NSTEPS 6
#define NGRAPH 64
#define NSEG (N_NODES * NTYPES)   // CSR segments keyed by dst*4+etype
#define PS 16                     // pooling splits per graph

static __device__ __forceinline__ float sigmoidf_(float x) { return 1.0f / (1.0f + expf(-x)); }

// ---------------- CSR build keyed by (dst*4 + etype) ----------------
__global__ void k_count(const int* __restrict__ dst, const int* __restrict__ ety,
                        int* __restrict__ deg) {
    int e = blockIdx.x * 256 + threadIdx.x;
    if (e < N_EDGES) atomicAdd(&deg[dst[e] * 4 + ety[e]], 1);
}

__global__ void k_scan1(const int* __restrict__ deg, int* __restrict__ rs, int* __restrict__ part) {
    __shared__ int sh[256];
    int t = threadIdx.x;
    int base = blockIdx.x * 1024 + t * 4;
    int v0 = (base + 0 < NSEG) ? deg[base + 0] : 0;
    int v1 = (base + 1 < NSEG) ? deg[base + 1] : 0;
    int v2 = (base + 2 < NSEG) ? deg[base + 2] : 0;
    int v3 = (base + 3 < NSEG) ? deg[base + 3] : 0;
    int s = v0 + v1 + v2 + v3;
    sh[t] = s;
    __syncthreads();
    for (int off = 1; off < 256; off <<= 1) {
        int x = (t >= off) ? sh[t - off] : 0;
        __syncthreads();
        sh[t] += x;
        __syncthreads();
    }
    int excl = sh[t] - s;
    if (t == 255) part[blockIdx.x] = sh[255];
    if (base + 0 < NSEG) rs[base + 0] = excl;
    if (base + 1 < NSEG) rs[base + 1] = excl + v0;
    if (base + 2 < NSEG) rs[base + 2] = excl + v0 + v1;
    if (base + 3 < NSEG) rs[base + 3] = excl + v0 + v1 + v2;
}

__global__ void k_scan2(int* __restrict__ part, int* __restrict__ rs, int nb) {
    if (threadIdx.x == 0 && blockIdx.x == 0) {
        int run = 0;
        for (int i = 0; i < nb; ++i) { int v = part[i]; part[i] = run; run += v; }
        rs[NSEG] = run;   // == N_EDGES
    }
}

__global__ void k_scan3(int* __restrict__ rs, const int* __restrict__ part) {
    int i = blockIdx.x * 256 + threadIdx.x;
    if (i < NSEG) rs[i] += part[i >> 10];
}

// colidx[pos] = float-offset of h row: src*64
__global__ void k_fill(const int* __restrict__ src, const int* __restrict__ dst,
                       const int* __restrict__ ety, const int* __restrict__ rs,
                       int* __restrict__ cur, int* __restrict__ colidx) {
    int e = blockIdx.x * 256 + threadIdx.x;
    if (e < N_EDGES) {
        int key = dst[e] * 4 + ety[e];
        int pos = rs[key] + atomicAdd(&cur[key], 1);
        colidx[pos] = src[e] * 64;
    }
}

// per-node per-type edge counts (for the eb bias term), packed int4
__global__ void k_cnt4(const int* __restrict__ rs, int* __restrict__ cnt4) {
    int n = blockIdx.x * 256 + threadIdx.x;
    if (n < N_NODES) {
        int a = rs[n * 4], b = rs[n * 4 + 1], c = rs[n * 4 + 2], d = rs[n * 4 + 3],
            e = rs[n * 4 + 4];
        int4 v; v.x = b - a; v.y = c - b; v.z = d - c; v.w = e - d;
        ((int4*)cnt4)[n] = v;
    }
}

// ---------------- weight prep: gate-interleaved (j*3+g) transposed GRU weights ----------------
__global__ void k_prep3(const float* __restrict__ Wh, const float* __restrict__ Bh,
                        const float* __restrict__ Wi, const float* __restrict__ Bi,
                        float* __restrict__ WhA, float* __restrict__ WiA,
                        float* __restrict__ biH, float* __restrict__ biA) {
    int idx = blockIdx.x * 256 + threadIdx.x;
    if (idx < 64 * 192) {
        int k = idx / 192, m = idx % 192;
        int j = m / 3, g = m % 3;
        WhA[idx] = Wh[(g * 64 + j) * 64 + k];
        WiA[idx] = Wi[(g * 64 + j) * 64 + k];
    }
    if (idx < 192) {
        int j = idx / 3, g = idx % 3;
        biH[idx] = Bh[g * 64 + j];
        biA[idx] = Bi[g * 64 + j];
    }
}

// ---------------- generic tiled GEMM: Y[N][M] = X[N][K] @ W[K][M] + bias (reduce layer) ------
__global__ __launch_bounds__(256) void k_gemm(const float* __restrict__ X, int ldx, int K,
                                              const float* __restrict__ W, int ldw,
                                              const float* __restrict__ bias,
                                              float* __restrict__ Y, float* __restrict__ Y2,
                                              int M) {
    __shared__ float sX[128 * 66];
    __shared__ float sW[64 * 64];
    int tid = threadIdx.x;
    int mtile = blockIdx.x * 64;
    int ntile = blockIdx.y * 128;
    int tc4 = (tid & 15) * 4;
    int tr = tid >> 4;
    float4 acc[8];
#pragma unroll
    for (int i = 0; i < 8; ++i) acc[i] = make_float4(0.f, 0.f, 0.f, 0.f);

    int nkc = K >> 6;
    for (int kc = 0; kc < nkc; ++kc) {
        if (kc) __syncthreads();
#pragma unroll
        for (int i = 0; i < 8; ++i) {
            int lin4 = (i * 256 + tid) * 4;
            int nl = lin4 >> 6, kk = lin4 & 63;
            int n = ntile + nl;
            float4 v = make_float4(0.f, 0.f, 0.f, 0.f);
            if (n < N_NODES) v = *(const float4*)(X + (size_t)n * ldx + kc * 64 + kk);
            float* d = sX + nl * 66 + kk;
            d[0] = v.x; d[1] = v.y; d[2] = v.z; d[3] = v.w;
        }
#pragma unroll
        for (int i = 0; i < 4; ++i) {
            int lin4 = (i * 256 + tid) * 4;
            int kk = lin4 >> 6, c = lin4 & 63;
            float4 v = *(const float4*)(W + (size_t)(kc * 64 + kk) * ldw + mtile + c);
            *(float4*)(sW + kk * 64 + c) = v;
        }
        __syncthreads();
        const float* xr = sX + tr * 8 * 66;
        const float* wr = sW + tc4;
        for (int kk = 0; kk < 64; kk += 2) {
            float4 wA = *(const float4*)(wr + kk * 64);
            float4 wB = *(const float4*)(wr + (kk + 1) * 64);
            float xA[8], xB[8];
#pragma unroll
            for (int i = 0; i < 8; ++i) { xA[i] = xr[i * 66 + kk]; xB[i] = xr[i * 66 + kk + 1]; }
#pragma unroll
            for (int i = 0; i < 8; ++i) {
                acc[i].x = fmaf(xA[i], wA.x, acc[i].x);
                acc[i].y = fmaf(xA[i], wA.y, acc[i].y);
                acc[i].z = fmaf(xA[i], wA.z, acc[i].z);
                acc[i].w = fmaf(xA[i], wA.w, acc[i].w);
            }
#pragma unroll
            for (int i = 0; i < 8; ++i) {
                acc[i].x = fmaf(xB[i], wB.x, acc[i].x);
                acc[i].y = fmaf(xB[i], wB.y, acc[i].y);
                acc[i].z = fmaf(xB[i], wB.z, acc[i].z);
                acc[i].w = fmaf(xB[i], wB.w, acc[i].w);
            }
        }
    }
    float4 bv = *(const float4*)(bias + mtile + tc4);
#pragma unroll
    for (int i = 0; i < 8; ++i) {
        int n = ntile + tr * 8 + i;
        if (n < N_NODES) {
            float4 y;
            y.x = acc[i].x + bv.x; y.y = acc[i].y + bv.y;
            y.z = acc[i].z + bv.z; y.w = acc[i].w + bv.w;
            *(float4*)(Y + (size_t)n * M + mtile + tc4) = y;
            if (Y2) *(float4*)(Y2 + (size_t)n * M + mtile + tc4) = y;
        }
    }
}

// ---------------- fused gather + S@eW + eb epilogue -> abuf ----------------
// Block: 256 thr, 32 dst nodes. Phase 1: each wave gathers a CONTIGUOUS CSR range
// (8 nodes x 4 types), 4-way unrolled edge loop -> ~4 outstanding loads/wave,
// 3 blocks/CU (49 KB LDS) -> ~48 in flight/CU, matching standalone k_gath's MLP.
// Phase 2: in-LDS GEMM K=256 with eW's NATIVE stacked [256][64] layout.
// Eliminates the 102 MB S buffer's write+read (200 MB/step fabric).
__global__ __launch_bounds__(256) void k_aggmm(const float* __restrict__ h,
                                               const int* __restrict__ rs,
                                               const int* __restrict__ colidx,
                                               const float* __restrict__ eW,
                                               const float* __restrict__ eb,
                                               const int* __restrict__ cnt4,
                                               float* __restrict__ Y) {
    __shared__ float sX[32 * 260];   // 32 nodes x K=256, pad 260
    __shared__ float sW[64 * 64];
    int tid = threadIdx.x;
    int ntile = blockIdx.x * 32;     // N % 32 == 0
    int wave = tid >> 6, lane = tid & 63;

    // ---- phase 1: gather. wave w handles segments for nodes [w*8, w*8+8) (contiguous CSR)
    for (int ii = 0; ii < 32; ++ii) {
        int idx = wave * 32 + ii;
        int nl = idx >> 2, t = idx & 3;
        int seg = (ntile + nl) * 4 + t;
        int beg = rs[seg], end = rs[seg + 1];   // wave-uniform
        float a0 = 0.f, a1 = 0.f, a2 = 0.f, a3 = 0.f;
        int s = beg;
        for (; s + 3 < end; s += 4) {
            int c0 = colidx[s], c1 = colidx[s + 1], c2 = colidx[s + 2], c3 = colidx[s + 3];
            a0 += h[(size_t)c0 + lane];
            a1 += h[(size_t)c1 + lane];
            a2 += h[(size_t)c2 + lane];
            a3 += h[(size_t)c3 + lane];
        }
        for (; s < end; ++s) a0 += h[(size_t)colidx[s] + lane];
        sX[nl * 260 + t * 64 + lane] = (a0 + a1) + (a2 + a3);
    }
    __syncthreads();

    // ---- phase 2: GEMM  a[32][64] = sX[32][256] @ eW[256][64]
    int tc4 = (tid & 15) * 4;
    int tr = tid >> 4;                // 16 row-groups x 2 nodes
    float4 acc0 = make_float4(0.f, 0.f, 0.f, 0.f);
    float4 acc1 = make_float4(0.f, 0.f, 0.f, 0.f);
    for (int kc = 0; kc < 4; ++kc) {
        if (kc) __syncthreads();
#pragma unroll
        for (int i = 0; i < 4; ++i) {
            int lin4 = (i * 256 + tid) * 4;
            int kk = lin4 >> 6, c = lin4 & 63;
            *(float4*)(sW + kk * 64 + c) = *(const float4*)(eW + (size_t)(kc * 64 + kk) * 64 + c);
        }
        __syncthreads();
        const float* x0 = sX + (tr * 2 + 0) * 260 + kc * 64;
        const float* x1 = sX + (tr * 2 + 1) * 260 + kc * 64;
        const float* wr = sW + tc4;
        for (int kk = 0; kk < 64; kk += 2) {
            float4 wA = *(const float4*)(wr + kk * 64);
            float4 wB = *(const float4*)(wr + (kk + 1) * 64);
            float xa0 = x0[kk], xb0 = x0[kk + 1];
            float xa1 = x1[kk], xb1 = x1[kk + 1];
            acc0.x = fmaf(xa0, wA.x, acc0.x); acc0.y = fmaf(xa0, wA.y, acc0.y);
            acc0.z = fmaf(xa0, wA.z, acc0.z); acc0.w = fmaf(xa0, wA.w, acc0.w);
            acc1.x = fmaf(xa1, wA.x, acc1.x); acc1.y = fmaf(xa1, wA.y, acc1.y);
            acc1.z = fmaf(xa1, wA.z, acc1.z); acc1.w = fmaf(xa1, wA.w, acc1.w);
            acc0.x = fmaf(xb0, wB.x, acc0.x); acc0.y = fmaf(xb0, wB.y, acc0.y);
            acc0.z = fmaf(xb0, wB.z, acc0.z); acc0.w = fmaf(xb0, wB.w, acc0.w);
            acc1.x = fmaf(xb1, wB.x, acc1.x); acc1.y = fmaf(xb1, wB.y, acc1.y);
            acc1.z = fmaf(xb1, wB.z, acc1.z); acc1.w = fmaf(xb1, wB.w, acc1.w);
        }
    }
    // ---- epilogue: + sum_t cnt_t * eb_t, store
    float4 e0 = *(const float4*)(eb + tc4);
    float4 e1 = *(const float4*)(eb + 64 + tc4);
    float4 e2 = *(const float4*)(eb + 128 + tc4);
    float4 e3 = *(const float4*)(eb + 192 + tc4);
#pragma unroll
    for (int i = 0; i < 2; ++i) {
        int n = ntile + tr * 2 + i;
        int4 c = *(const int4*)(cnt4 + (size_t)n * 4);
        float fx = (float)c.x, fy = (float)c.y, fz = (float)c.z, fw = (float)c.w;
        float4 y = (i == 0) ? acc0 : acc1;
        y.x += fx * e0.x + fy * e1.x + fz * e2.x + fw * e3.x;
        y.y += fx * e0.y + fy * e1.y + fz * e2.y + fw * e3.y;
        y.z += fx * e0.z + fy * e1.z + fz * e2.z + fw * e3.z;
        y.w += fx * e0.w + fy * e1.w + fz * e2.w + fw * e3.w;
        *(float4*)(Y + (size_t)n * 64 + tc4) = y;
    }
}

// ---------------- fused GRU: gi = a@WiA, gh = h@WhA, gate epilogue (32-node tile) ----------
// 41.5 KB LDS -> 3 blocks/CU (R7's 64-node version was 58 KB -> 2 blocks/CU).
#define GRUF3_INNER(ACC)                                                           \
    for (int kk = 0; kk < 32; kk += 2) {                                           \
        float4 w0 = *(const float4*)(wr + kk * 192);                               \
        float4 w1 = *(const float4*)(wr + kk * 192 + 4);                           \
        float4 w2 = *(const float4*)(wr + kk * 192 + 8);                           \
        float4 u0 = *(const float4*)(wr + (kk + 1) * 192);                         \
        float4 u1 = *(const float4*)(wr + (kk + 1) * 192 + 4);                     \
        float4 u2 = *(const float4*)(wr + (kk + 1) * 192 + 8);                     \
        float xA[2], xB[2];                                                        \
        _Pragma("unroll")                                                          \
        for (int i = 0; i < 2; ++i) {                                              \
            xA[i] = xr[i * 66 + kk]; xB[i] = xr[i * 66 + kk + 1];                  \
        }                                                                          \
        _Pragma("unroll")                                                          \
        for (int i = 0; i < 2; ++i) {                                              \
            ACC[i][0]  = fmaf(xA[i], w0.x, ACC[i][0]);                             \
            ACC[i][1]  = fmaf(xA[i], w0.y, ACC[i][1]);                             \
            ACC[i][2]  = fmaf(xA[i], w0.z, ACC[i][2]);                             \
            ACC[i][3]  = fmaf(xA[i], w0.w, ACC[i][3]);                             \
            ACC[i][4]  = fmaf(xA[i], w1.x, ACC[i][4]);                             \
            ACC[i][5]  = fmaf(xA[i], w1.y, ACC[i][5]);                             \
            ACC[i][6]  = fmaf(xA[i], w1.z, ACC[i][6]);                             \
            ACC[i][7]  = fmaf(xA[i], w1.w, ACC[i][7]);                             \
            ACC[i][8]  = fmaf(xA[i], w2.x, ACC[i][8]);                             \
            ACC[i][9]  = fmaf(xA[i], w2.y, ACC[i][9]);                             \
            ACC[i][10] = fmaf(xA[i], w2.z, ACC[i][10]);                            \
            ACC[i][11] = fmaf(xA[i], w2.w, ACC[i][11]);                            \
        }                                                                          \
        _Pragma("unroll")                                                          \
        for (int i = 0; i < 2; ++i) {                                              \
            ACC[i][0]  = fmaf(xB[i], u0.x, ACC[i][0]);                             \
            ACC[i][1]  = fmaf(xB[i], u0.y, ACC[i][1]);                             \
            ACC[i][2]  = fmaf(xB[i], u0.z, ACC[i][2]);                             \
            ACC[i][3]  = fmaf(xB[i], u0.w, ACC[i][3]);                             \
            ACC[i][4]  = fmaf(xB[i], u1.x, ACC[i][4]);                             \
            ACC[i][5]  = fmaf(xB[i], u1.y, ACC[i][5]);                             \
            ACC[i][6]  = fmaf(xB[i], u1.z, ACC[i][6]);                             \
            ACC[i][7]  = fmaf(xB[i], u1.w, ACC[i][7]);                             \
            ACC[i][8]  = fmaf(xB[i], u2.x, ACC[i][8]);                             \
            ACC[i][9]  = fmaf(xB[i], u2.y, ACC[i][9]);                             \
            ACC[i][10] = fmaf(xB[i], u2.z, ACC[i][10]);                            \
            ACC[i][11] = fmaf(xB[i], u2.w, ACC[i][11]);                            \
        }                                                                          \
    }

__global__ __launch_bounds__(256) void k_gruF3(const float* __restrict__ A,
                                               const float* __restrict__ WiA,
                                               const float* __restrict__ WhA,
                                               const float* __restrict__ biA,
                                               const float* __restrict__ biH,
                                               float* __restrict__ H) {
    __shared__ float sA[32 * 66];
    __shared__ float sH[32 * 66];
    __shared__ float sW[32 * 192];
    int tid = threadIdx.x;
    int ntile = blockIdx.x * 32;   // N % 32 == 0

    // stage a-tile and h-tile (32 nodes x 64)
#pragma unroll
    for (int i = 0; i < 2; ++i) {
        int lin4 = (i * 256 + tid) * 4;
        int nl = lin4 >> 6, kk = lin4 & 63;
        int n = ntile + nl;
        float4 va = *(const float4*)(A + (size_t)n * 64 + kk);
        float4 vh = *(const float4*)(H + (size_t)n * 64 + kk);
        float* da = sA + nl * 66 + kk;
        da[0] = va.x; da[1] = va.y; da[2] = va.z; da[3] = va.w;
        float* dh = sH + nl * 66 + kk;
        dh[0] = vh.x; dh[1] = vh.y; dh[2] = vh.z; dh[3] = vh.w;
    }
    int tc = tid & 15, tr = tid >> 4;   // 16 row-groups x 2 nodes; 16 col-groups x 12
    float accI[2][12], accH[2][12];
#pragma unroll
    for (int i = 0; i < 2; ++i)
#pragma unroll
        for (int c = 0; c < 12; ++c) { accI[i][c] = 0.f; accH[i][c] = 0.f; }

    const float* wr = sW + tc * 12;
    for (int kc = 0; kc < 2; ++kc) {
        __syncthreads();   // (first iter: also covers sA/sH staging)
#pragma unroll
        for (int i = 0; i < 6; ++i) {
            int lin4 = (i * 256 + tid) * 4;
            *(float4*)(sW + lin4) = *(const float4*)(WiA + (size_t)kc * 32 * 192 + lin4);
        }
        __syncthreads();
        {
            const float* xr = sA + tr * 2 * 66 + kc * 32;
            GRUF3_INNER(accI)
        }
        __syncthreads();
#pragma unroll
        for (int i = 0; i < 6; ++i) {
            int lin4 = (i * 256 + tid) * 4;
            *(float4*)(sW + lin4) = *(const float4*)(WhA + (size_t)kc * 32 * 192 + lin4);
        }
        __syncthreads();
        {
            const float* xr = sH + tr * 2 * 66 + kc * 32;
            GRUF3_INNER(accH)
        }
    }

    // GRU gate epilogue
    float bI[12], bH[12];
    {
        float4 a0 = *(const float4*)(biA + tc * 12);
        float4 a1 = *(const float4*)(biA + tc * 12 + 4);
        float4 a2 = *(const float4*)(biA + tc * 12 + 8);
        bI[0] = a0.x; bI[1] = a0.y; bI[2] = a0.z; bI[3] = a0.w;
        bI[4] = a1.x; bI[5] = a1.y; bI[6] = a1.z; bI[7] = a1.w;
        bI[8] = a2.x; bI[9] = a2.y; bI[10] = a2.z; bI[11] = a2.w;
        float4 h0_ = *(const float4*)(biH + tc * 12);
        float4 h1_ = *(const float4*)(biH + tc * 12 + 4);
        float4 h2_ = *(const float4*)(biH + tc * 12 + 8);
        bH[0] = h0_.x; bH[1] = h0_.y; bH[2] = h0_.z; bH[3] = h0_.w;
        bH[4] = h1_.x; bH[5] = h1_.y; bH[6] = h1_.z; bH[7] = h1_.w;
        bH[8] = h2_.x; bH[9] = h2_.y; bH[10] = h2_.z; bH[11] = h2_.w;
    }
#pragma unroll
    for (int i = 0; i < 2; ++i) {
        int nl = tr * 2 + i;
        int n = ntile + nl;
        const float* hrow = sH + nl * 66 + tc * 4;   // old h (staged copy)
        float res[4];
#pragma unroll
        for (int jj = 0; jj < 4; ++jj) {
            int c = jj * 3;
            float r = sigmoidf_(accI[i][c] + bI[c] + accH[i][c] + bH[c]);
            float z = sigmoidf_(accI[i][c + 1] + bI[c + 1] + accH[i][c + 1] + bH[c + 1]);
            float nn = tanhf(accI[i][c + 2] + bI[c + 2] + r * (accH[i][c + 2] + bH[c + 2]));
            res[jj] = (1.f - z) * nn + z * hrow[jj];
        }
        float4 o; o.x = res[0]; o.y = res[1]; o.z = res[2]; o.w = res[3];
        *(float4*)(H + (size_t)n * 64 + tc * 4) = o;
    }
}

// ---------------- pooling: segmented, atomic-free, multi-block per graph ----------------
__global__ void k_bounds(const int* __restrict__ gid, int* __restrict__ start) {
    int n = blockIdx.x * 256 + threadIdx.x;
    if (n < N_NODES) {
        int g = gid[n];
        if (n == 0) {
            for (int x = 0; x <= g; ++x) start[x] = 0;
        } else {
            int pg = gid[n - 1];
            for (int x = pg + 1; x <= g; ++x) start[x] = n;
        }
        if (n == N_NODES - 1) {
            for (int x = g + 1; x <= NGRAPH; ++x) start[x] = N_NODES;
        }
    }
}

__global__ void k_gate2(const float* __restrict__ H, const float* __restrict__ H0,
                        const float* __restrict__ gW, const float* __restrict__ gb,
                        float* __restrict__ gate) {
    int l = threadIdx.x & 63;
    int n = blockIdx.x * 4 + (threadIdx.x >> 6);
    float v = H[(size_t)n * 64 + l] * gW[l] + H0[(size_t)n * 64 + l] * gW[64 + l];
    for (int off = 32; off > 0; off >>= 1) v += __shfl_xor(v, off, 64);
    if (l == 0) gate[n] = v + gb[0];
}

__global__ __launch_bounds__(64) void k_poolA(const float* __restrict__ gate,
                                              const int* __restrict__ start,
                                              float* __restrict__ pmax) {
    int g = blockIdx.x, s = blockIdx.y;
    int beg = start[g], len = start[g + 1] - beg;
    int sb = beg + (int)((long long)len * s / PS);
    int se = beg + (int)((long long)len * (s + 1) / PS);
    float m = -INFINITY;
    for (int n = sb + threadIdx.x; n < se; n += 64) m = fmaxf(m, gate[n]);
    for (int off = 32; off > 0; off >>= 1) m = fmaxf(m, __shfl_xor(m, off, 64));
    if (threadIdx.x == 0) pmax[g * PS + s] = m;
}

__global__ void k_poolB(const float* __restrict__ pmax, float* __restrict__ gm) {
    int g = threadIdx.x;  // 64 threads
    float m = -INFINITY;
    for (int s = 0; s < PS; ++s) m = fmaxf(m, pmax[g * PS + s]);
    if (!isfinite(m)) m = 0.0f;   // reference's empty-graph guard
    gm[g] = m;
}

__global__ __launch_bounds__(256) void k_poolC(const float* __restrict__ H,
                                               const float* __restrict__ H0,
                                               const float* __restrict__ gate,
                                               const int* __restrict__ start,
                                               const float* __restrict__ gm,
                                               float* __restrict__ pnum,
                                               float* __restrict__ pden) {
    int g = blockIdx.x, s = blockIdx.y;
    int beg = start[g], len = start[g + 1] - beg;
    int sb = beg + (int)((long long)len * s / PS);
    int se = beg + (int)((long long)len * (s + 1) / PS);
    int t = threadIdx.x;
    int lane = t & 63, wave = t >> 6;
    float m = gm[g];
    __shared__ float shh[4][64], sh0[4][64], ses[4];
    float ah = 0.f, ah0 = 0.f, es = 0.f;
    for (int n = sb + wave; n < se; n += 4) {
        float e = expf(gate[n] - m);
        es += e;
        ah  += e * H [(size_t)n * 64 + lane];
        ah0 += e * H0[(size_t)n * 64 + lane];
    }
    shh[wave][lane] = ah; sh0[wave][lane] = ah0;
    if (lane == 0) ses[wave] = es;
    __syncthreads();
    if (wave == 0) {
        float r  = shh[0][lane] + shh[1][lane] + shh[2][lane] + shh[3][lane];
        float r0 = sh0[0][lane] + sh0[1][lane] + sh0[2][lane] + sh0[3][lane];
        int base = (g * PS + s) * 128;
        pnum[base + lane]      = r;
        pnum[base + 64 + lane] = r0;
        if (lane == 0) pden[g * PS + s] = ses[0] + ses[1] + ses[2] + ses[3];
    }
}

__global__ __launch_bounds__(128) void k_poolD(const float* __restrict__ pnum,
                                               const float* __restrict__ pden,
                                               float* __restrict__ ro) {
    int g = blockIdx.x;
    int c = threadIdx.x;
    float den = 0.f;
    for (int s = 0; s < PS; ++s) den += pden[g * PS + s];
    float nu = 0.f;
    for (int s = 0; s < PS; ++s) nu += pnum[(g * PS + s) * 128 + c];
    ro[g * 128 + c] = (den > 0.f) ? nu / den : 0.f;
}

__global__ void k_logits(const float* __restrict__ ro, const float* __restrict__ oW,
                         const float* __restrict__ ob, float* __restrict__ out) {
    int t = threadIdx.x;
    int b = t >> 1;
    int c = t & 1;
    float acc = ob[c];
    for (int k = 0; k < 128; ++k) acc = fmaf(ro[b * 128 + k], oW[k * 2 + c], acc);
    out[b * 2 + c] = acc;
}

extern "C" void kernel_launch(void* const* d_in, const int* in_sizes, int n_in,
                              void* d_out, int out_size, void* d_ws, size_t ws_size,
                              hipStream_t stream) {
    (void)in_sizes; (void)n_in; (void)out_size; (void)ws_size;
    const float* ann = (const float*)d_in[0];
    const int* src   = (const int*)d_in[1];
    const int* dst   = (const int*)d_in[2];
    const int* ety   = (const int*)d_in[3];
    const int* gid   = (const int*)d_in[4];
    const float* rW  = (const float*)d_in[5];
    const float* rb  = (const float*)d_in[6];
    const float* eW  = (const float*)d_in[7];
    const float* eb  = (const float*)d_in[8];
    const float* Wi  = (const float*)d_in[9];
    const float* Bi  = (const float*)d_in[10];
    const float* Wh  = (const float*)d_in[11];
    const float* Bh  = (const float*)d_in[12];
    const float* gW  = (const float*)d_in[13];
    const float* gb  = (const float*)d_in[14];
    const float* oW  = (const float*)d_in[15];
    const float* ob  = (const float*)d_in[16];
    float* out = (float*)d_out;

    char* p = (char*)d_ws;
    auto take = [&](size_t nbytes) -> void* {
        void* r = (void*)p;
        p += (nbytes + 255) & ~((size_t)255);
        return r;
    };
    float* h0    = (float*)take((size_t)N_NODES * 64 * 4);
    float* h     = (float*)take((size_t)N_NODES * 64 * 4);
    float* abuf  = (float*)take((size_t)N_NODES * 64 * 4);
    float* WhA   = (float*)take(64 * 192 * 4);
    float* WiA   = (float*)take(64 * 192 * 4);
    float* biH   = (float*)take(192 * 4);
    float* biA   = (float*)take(192 * 4);
    int* deg     = (int*)take((size_t)NSEG * 4);
    int* cur     = (int*)take((size_t)NSEG * 4);
    int* rs      = (int*)take((size_t)(NSEG + 1) * 4);
    int* part    = (int*)take(2048);
    int* colidx  = (int*)take((size_t)N_EDGES * 4);
    int* cnt4    = (int*)take((size_t)N_NODES * 4 * 4);
    float* gate  = (float*)take((size_t)N_NODES * 4);
    int* start   = (int*)take((size_t)(NGRAPH + 1) * 4);
    float* pmax  = (float*)take(NGRAPH * PS * 4);
    float* gm    = (float*)take(NGRAPH * 4);
    float* pnum  = (float*)take((size_t)NGRAPH * PS * 128 * 4);
    float* pden  = (float*)take(NGRAPH * PS * 4);
    float* ro    = (float*)take(NGRAPH * 128 * 4);

    // ---- CSR build (keyed by dst*4+etype)
    hipMemsetAsync(deg, 0, (size_t)NSEG * 4, stream);
    hipMemsetAsync(cur, 0, (size_t)NSEG * 4, stream);
    k_count<<<(N_EDGES + 255) / 256, 256, 0, stream>>>(dst, ety, deg);
    int nb = (NSEG + 1023) / 1024;  // 391
    k_scan1<<<nb, 256, 0, stream>>>(deg, rs, part);
    k_scan2<<<1, 64, 0, stream>>>(part, rs, nb);
    k_scan3<<<(NSEG + 255) / 256, 256, 0, stream>>>(rs, part);
    k_fill<<<(N_EDGES + 255) / 256, 256, 0, stream>>>(src, dst, ety, rs, cur, colidx);
    k_cnt4<<<(N_NODES + 255) / 256, 256, 0, stream>>>(rs, cnt4);

    // ---- weight prep + graph bounds
    k_prep3<<<48, 256, 0, stream>>>(Wh, Bh, Wi, Bi, WhA, WiA, biH, biA);
    k_bounds<<<(N_NODES + 255) / 256, 256, 0, stream>>>(gid, start);

    int ntiles = (N_NODES + 127) / 128;  // 782

    // ---- reduce layer: h = h0 = ann @ rW + rb
    k_gemm<<<dim3(1, ntiles), 256, 0, stream>>>(ann, ASIZE, ASIZE, rW, 64, rb, h, h0, 64);

    // ---- message-passing steps: fused gather+transform, then fused GRU
    for (int s = 0; s < NSTEPS; ++s) {
        k_aggmm<<<N_NODES / 32, 256, 0, stream>>>(h, rs, colidx, eW, eb, cnt4, abuf);
        k_gruF3<<<N_NODES / 32, 256, 0, stream>>>(abuf, WiA, WhA, biA, biH, h);
    }

    // ---- pooling + classifier (atomic-free, multi-block)
    k_gate2<<<N_NODES / 4, 256, 0, stream>>>(h, h0, gW, gb, gate);
    k_poolA<<<dim3(NGRAPH, PS), 64, 0, stream>>>(gate, start, pmax);
    k_poolB<<<1, 64, 0, stream>>>(pmax, gm);
    k_poolC<<<dim3(NGRAPH, PS), 256, 0, stream>>>(h, h0, gate, start, gm, pnum, pden);
    k_poolD<<<NGRAPH, 128, 0, stream>>>(pnum, pden, ro);
    k_logits<<<1, 128, 0, stream>>>(ro, oW, ob, out);
}

// Round 9
// 1600.966 us; speedup vs baseline: 2.7365x; 2.7365x over previous
//
#include <hip/hip_runtime.h>
#include <cstdint>
#include <cstddef>

#define N_NODES 100000
#define N_EDGES 1200000
#define ASIZE 256
#define HSIZE 64
#define NTYPES 4
#define NSTEPS 6
#define NGRAPH 64
#define PS 16   // pooling splits per graph

static __device__ __forceinline__ float sigmoidf_(float x) { return 1.0f / (1.0f + expf(-x)); }

// ---------------- CSR build (by dst) ----------------
__global__ void k_count(const int* __restrict__ dst, int* __restrict__ deg) {
    int e = blockIdx.x * 256 + threadIdx.x;
    if (e < N_EDGES) atomicAdd(&deg[dst[e]], 1);
}

__global__ void k_scan1(const int* __restrict__ deg, int* __restrict__ rs, int* __restrict__ part) {
    __shared__ int sh[256];
    int t = threadIdx.x;
    int base = blockIdx.x * 1024 + t * 4;
    int v0 = (base + 0 < N_NODES) ? deg[base + 0] : 0;
    int v1 = (base + 1 < N_NODES) ? deg[base + 1] : 0;
    int v2 = (base + 2 < N_NODES) ? deg[base + 2] : 0;
    int v3 = (base + 3 < N_NODES) ? deg[base + 3] : 0;
    int s = v0 + v1 + v2 + v3;
    sh[t] = s;
    __syncthreads();
    for (int off = 1; off < 256; off <<= 1) {
        int x = (t >= off) ? sh[t - off] : 0;
        __syncthreads();
        sh[t] += x;
        __syncthreads();
    }
    int excl = sh[t] - s;
    if (t == 255) part[blockIdx.x] = sh[255];
    if (base + 0 < N_NODES) rs[base + 0] = excl;
    if (base + 1 < N_NODES) rs[base + 1] = excl + v0;
    if (base + 2 < N_NODES) rs[base + 2] = excl + v0 + v1;
    if (base + 3 < N_NODES) rs[base + 3] = excl + v0 + v1 + v2;
}

__global__ void k_scan2(int* __restrict__ part, int* __restrict__ rs, int nb) {
    if (threadIdx.x == 0 && blockIdx.x == 0) {
        int run = 0;
        for (int i = 0; i < nb; ++i) { int v = part[i]; part[i] = run; run += v; }
        rs[N_NODES] = run;
    }
}

__global__ void k_scan3(int* __restrict__ rs, const int* __restrict__ part) {
    int i = blockIdx.x * 256 + threadIdx.x;
    if (i < N_NODES) rs[i] += part[i >> 10];
}

// colidx holds a precomputed float-offset into buf1: src*448 + 192 + ety*64
__global__ void k_fill(const int* __restrict__ src, const int* __restrict__ dst,
                       const int* __restrict__ ety, const int* __restrict__ rs,
                       int* __restrict__ cur, int* __restrict__ colidx) {
    int e = blockIdx.x * 256 + threadIdx.x;
    if (e < N_EDGES) {
        int d = dst[e];
        int pos = rs[d] + atomicAdd(&cur[d], 1);
        colidx[pos] = src[e] * 448 + 192 + ety[e] * 64;
    }
}

// ---------------- weight prep ----------------
// W448[k][m]: m<192 -> Wh[(g*64+j)][k] with m=j*3+g (gate-interleaved gh cols)
//             m>=192 -> eW[t][k][jj] with m=192+t*64+jj (trans cols)
// bias448: m<192 -> Bh[g*64+j]; else eb[t*64+jj]
// WiA[k][j*3+g] = Wi[(g*64+j)][k]; biA[j*3+g] = Bi[g*64+j]
__global__ void k_prep2(const float* __restrict__ Wh, const float* __restrict__ Bh,
                        const float* __restrict__ eW, const float* __restrict__ eb,
                        const float* __restrict__ Wi, const float* __restrict__ Bi,
                        float* __restrict__ W448, float* __restrict__ bias448,
                        float* __restrict__ WiA, float* __restrict__ biA) {
    int idx = blockIdx.x * 256 + threadIdx.x;
    if (idx < 64 * 448) {
        int k = idx / 448, m = idx % 448;
        float v;
        if (m < 192) {
            int j = m / 3, g = m % 3;
            v = Wh[(g * 64 + j) * 64 + k];
        } else {
            v = eW[(size_t)(m - 192 >> 6) * 4096 + k * 64 + ((m - 192) & 63)];
        }
        W448[idx] = v;
    }
    if (idx < 64 * 192) {
        int k = idx / 192, m = idx % 192;
        int j = m / 3, g = m % 3;
        WiA[idx] = Wi[(g * 64 + j) * 64 + k];
    }
    if (idx < 448) {
        bias448[idx] = (idx < 192) ? Bh[(idx % 3) * 64 + idx / 3] : eb[idx - 192];
    }
    if (idx < 192) {
        biA[idx] = Bi[(idx % 3) * 64 + idx / 3];
    }
}

// ---------------- generic tiled GEMM: Y[N][M] = X[N][K] @ W[K][M] + bias ----------------
// block: 256 thr; tile 128 nodes x 64 cols (mtile = blockIdx.x*64); thread micro 8x4.
__global__ __launch_bounds__(256) void k_gemm(const float* __restrict__ X, int ldx, int K,
                                              const float* __restrict__ W, int ldw,
                                              const float* __restrict__ bias,
                                              float* __restrict__ Y, float* __restrict__ Y2,
                                              int M) {
    __shared__ float sX[128 * 66];
    __shared__ float sW[64 * 64];
    int tid = threadIdx.x;
    int mtile = blockIdx.x * 64;
    int ntile = blockIdx.y * 128;
    int tc4 = (tid & 15) * 4;
    int tr = tid >> 4;
    float4 acc[8];
#pragma unroll
    for (int i = 0; i < 8; ++i) acc[i] = make_float4(0.f, 0.f, 0.f, 0.f);

    int nkc = K >> 6;
    for (int kc = 0; kc < nkc; ++kc) {
        if (kc) __syncthreads();
#pragma unroll
        for (int i = 0; i < 8; ++i) {
            int lin4 = (i * 256 + tid) * 4;
            int nl = lin4 >> 6, kk = lin4 & 63;
            int n = ntile + nl;
            float4 v = make_float4(0.f, 0.f, 0.f, 0.f);
            if (n < N_NODES) v = *(const float4*)(X + (size_t)n * ldx + kc * 64 + kk);
            float* d = sX + nl * 66 + kk;
            d[0] = v.x; d[1] = v.y; d[2] = v.z; d[3] = v.w;
        }
#pragma unroll
        for (int i = 0; i < 4; ++i) {
            int lin4 = (i * 256 + tid) * 4;
            int kk = lin4 >> 6, c = lin4 & 63;
            float4 v = *(const float4*)(W + (size_t)(kc * 64 + kk) * ldw + mtile + c);
            *(float4*)(sW + kk * 64 + c) = v;
        }
        __syncthreads();
        const float* xr = sX + tr * 8 * 66;
        const float* wr = sW + tc4;
        for (int kk = 0; kk < 64; kk += 2) {
            float4 wA = *(const float4*)(wr + kk * 64);
            float4 wB = *(const float4*)(wr + (kk + 1) * 64);
            float xA[8], xB[8];
#pragma unroll
            for (int i = 0; i < 8; ++i) { xA[i] = xr[i * 66 + kk]; xB[i] = xr[i * 66 + kk + 1]; }
#pragma unroll
            for (int i = 0; i < 8; ++i) {
                acc[i].x = fmaf(xA[i], wA.x, acc[i].x);
                acc[i].y = fmaf(xA[i], wA.y, acc[i].y);
                acc[i].z = fmaf(xA[i], wA.z, acc[i].z);
                acc[i].w = fmaf(xA[i], wA.w, acc[i].w);
            }
#pragma unroll
            for (int i = 0; i < 8; ++i) {
                acc[i].x = fmaf(xB[i], wB.x, acc[i].x);
                acc[i].y = fmaf(xB[i], wB.y, acc[i].y);
                acc[i].z = fmaf(xB[i], wB.z, acc[i].z);
                acc[i].w = fmaf(xB[i], wB.w, acc[i].w);
            }
        }
    }
    float4 bv = *(const float4*)(bias + mtile + tc4);
#pragma unroll
    for (int i = 0; i < 8; ++i) {
        int n = ntile + tr * 8 + i;
        if (n < N_NODES) {
            float4 y;
            y.x = acc[i].x + bv.x; y.y = acc[i].y + bv.y;
            y.z = acc[i].z + bv.z; y.w = acc[i].w + bv.w;
            *(float4*)(Y + (size_t)n * M + mtile + tc4) = y;
            if (Y2) *(float4*)(Y2 + (size_t)n * M + mtile + tc4) = y;
        }
    }
}

// ---------------- edge aggregate: a[n] = sum of incoming trans rows from buf1 ----------------
// standalone, max-occupancy (VGPR 8, no LDS); 4-way unrolled edge loop (R6-proven MLP).
__global__ void k_aggregate(const float* __restrict__ buf1, const int* __restrict__ rs,
                            const int* __restrict__ colidx, float* __restrict__ a) {
    int l = threadIdx.x & 63;
    int n = blockIdx.x * 4 + (threadIdx.x >> 6);  // 25000 blocks * 4 = N exactly
    int beg = rs[n], end = rs[n + 1];             // wave-uniform
    float a0 = 0.f, a1 = 0.f, a2 = 0.f, a3 = 0.f;
    int s = beg;
    for (; s + 3 < end; s += 4) {
        int c0 = colidx[s], c1 = colidx[s + 1], c2 = colidx[s + 2], c3 = colidx[s + 3];
        a0 += buf1[(size_t)c0 + l];
        a1 += buf1[(size_t)c1 + l];
        a2 += buf1[(size_t)c2 + l];
        a3 += buf1[(size_t)c3 + l];
    }
    for (; s < end; ++s) a0 += buf1[(size_t)colidx[s] + l];
    a[(size_t)n * 64 + l] = (a0 + a1) + (a2 + a3);
}

// ---------------- fused gi-GEMM + GRU gate epilogue (exact R4 kernel, VGPR 68 proven) -------
// tile: 64 nodes x 192 cols (cols arranged j*3+g); thread: 4 nodes x 12 cols.
// gh (bias included) read from buf1 cols 0..191 (same j*3+g arrangement). H updated in place.
__global__ __launch_bounds__(256) void k_gruF(const float* __restrict__ A,
                                              const float* __restrict__ WiA,
                                              const float* __restrict__ biA,
                                              const float* __restrict__ buf1,
                                              float* __restrict__ H) {
    __shared__ float sX[64 * 34];
    __shared__ float sW[32 * 192];
    int tid = threadIdx.x;
    int ntile = blockIdx.x * 64;
    int tc = tid & 15;
    int tr = tid >> 4;
    float acc[4][12];
#pragma unroll
    for (int i = 0; i < 4; ++i)
#pragma unroll
        for (int c = 0; c < 12; ++c) acc[i][c] = 0.f;

    for (int kc = 0; kc < 2; ++kc) {
        if (kc) __syncthreads();
        // stage X (a) tile [64 nodes][32 k] stride 34
#pragma unroll
        for (int i = 0; i < 2; ++i) {
            int lin4 = (i * 256 + tid) * 4;
            int nl = lin4 >> 5, kk = lin4 & 31;
            int n = ntile + nl;
            float4 v = make_float4(0.f, 0.f, 0.f, 0.f);
            if (n < N_NODES) v = *(const float4*)(A + (size_t)n * 64 + kc * 32 + kk);
            float* d = sX + nl * 34 + kk;
            d[0] = v.x; d[1] = v.y; d[2] = v.z; d[3] = v.w;
        }
        // stage W chunk [32 k][192 m]
        {
            int kk = tid >> 3, c = (tid & 7) * 24;
            const float* srcp = WiA + (size_t)(kc * 32 + kk) * 192 + c;
            float* d = sW + kk * 192 + c;
#pragma unroll
            for (int u = 0; u < 6; ++u) *(float4*)(d + 4 * u) = *(const float4*)(srcp + 4 * u);
        }
        __syncthreads();
        const float* xr = sX + tr * 4 * 34;
        const float* wr = sW + tc * 12;
        for (int kk = 0; kk < 32; kk += 2) {
            float4 w0 = *(const float4*)(wr + kk * 192);
            float4 w1 = *(const float4*)(wr + kk * 192 + 4);
            float4 w2 = *(const float4*)(wr + kk * 192 + 8);
            float4 u0 = *(const float4*)(wr + (kk + 1) * 192);
            float4 u1 = *(const float4*)(wr + (kk + 1) * 192 + 4);
            float4 u2 = *(const float4*)(wr + (kk + 1) * 192 + 8);
            float xA[4], xB[4];
#pragma unroll
            for (int i = 0; i < 4; ++i) { xA[i] = xr[i * 34 + kk]; xB[i] = xr[i * 34 + kk + 1]; }
#pragma unroll
            for (int i = 0; i < 4; ++i) {
                acc[i][0]  = fmaf(xA[i], w0.x, acc[i][0]);
                acc[i][1]  = fmaf(xA[i], w0.y, acc[i][1]);
                acc[i][2]  = fmaf(xA[i], w0.z, acc[i][2]);
                acc[i][3]  = fmaf(xA[i], w0.w, acc[i][3]);
                acc[i][4]  = fmaf(xA[i], w1.x, acc[i][4]);
                acc[i][5]  = fmaf(xA[i], w1.y, acc[i][5]);
                acc[i][6]  = fmaf(xA[i], w1.z, acc[i][6]);
                acc[i][7]  = fmaf(xA[i], w1.w, acc[i][7]);
                acc[i][8]  = fmaf(xA[i], w2.x, acc[i][8]);
                acc[i][9]  = fmaf(xA[i], w2.y, acc[i][9]);
                acc[i][10] = fmaf(xA[i], w2.z, acc[i][10]);
                acc[i][11] = fmaf(xA[i], w2.w, acc[i][11]);
            }
#pragma unroll
            for (int i = 0; i < 4; ++i) {
                acc[i][0]  = fmaf(xB[i], u0.x, acc[i][0]);
                acc[i][1]  = fmaf(xB[i], u0.y, acc[i][1]);
                acc[i][2]  = fmaf(xB[i], u0.z, acc[i][2]);
                acc[i][3]  = fmaf(xB[i], u0.w, acc[i][3]);
                acc[i][4]  = fmaf(xB[i], u1.x, acc[i][4]);
                acc[i][5]  = fmaf(xB[i], u1.y, acc[i][5]);
                acc[i][6]  = fmaf(xB[i], u1.z, acc[i][6]);
                acc[i][7]  = fmaf(xB[i], u1.w, acc[i][7]);
                acc[i][8]  = fmaf(xB[i], u2.x, acc[i][8]);
                acc[i][9]  = fmaf(xB[i], u2.y, acc[i][9]);
                acc[i][10] = fmaf(xB[i], u2.z, acc[i][10]);
                acc[i][11] = fmaf(xB[i], u2.w, acc[i][11]);
            }
        }
    }
    // epilogue: GRU gate math
    float bb[12];
    {
        float4 b0 = *(const float4*)(biA + tc * 12);
        float4 b1 = *(const float4*)(biA + tc * 12 + 4);
        float4 b2 = *(const float4*)(biA + tc * 12 + 8);
        bb[0] = b0.x; bb[1] = b0.y; bb[2] = b0.z; bb[3] = b0.w;
        bb[4] = b1.x; bb[5] = b1.y; bb[6] = b1.z; bb[7] = b1.w;
        bb[8] = b2.x; bb[9] = b2.y; bb[10] = b2.z; bb[11] = b2.w;
    }
#pragma unroll
    for (int i = 0; i < 4; ++i) {
        int n = ntile + tr * 4 + i;
        if (n >= N_NODES) continue;
        const float* ghp = buf1 + (size_t)n * 448 + tc * 12;
        float gg[12];
        float4 g0 = *(const float4*)(ghp);
        float4 g1 = *(const float4*)(ghp + 4);
        float4 g2 = *(const float4*)(ghp + 8);
        gg[0] = g0.x; gg[1] = g0.y; gg[2] = g0.z; gg[3] = g0.w;
        gg[4] = g1.x; gg[5] = g1.y; gg[6] = g1.z; gg[7] = g1.w;
        gg[8] = g2.x; gg[9] = g2.y; gg[10] = g2.z; gg[11] = g2.w;
        float4 hv = *(const float4*)(H + (size_t)n * 64 + tc * 4);
        float res[4];
#pragma unroll
        for (int jj = 0; jj < 4; ++jj) {
            int c = jj * 3;
            float r = sigmoidf_(acc[i][c] + bb[c] + gg[c]);
            float z = sigmoidf_(acc[i][c + 1] + bb[c + 1] + gg[c + 1]);
            float nn = tanhf(acc[i][c + 2] + bb[c + 2] + r * gg[c + 2]);
            float hj = (jj == 0) ? hv.x : (jj == 1) ? hv.y : (jj == 2) ? hv.z : hv.w;
            res[jj] = (1.f - z) * nn + z * hj;
        }
        float4 o; o.x = res[0]; o.y = res[1]; o.z = res[2]; o.w = res[3];
        *(float4*)(H + (size_t)n * 64 + tc * 4) = o;
    }
}

// ---------------- pooling: segmented, atomic-free, multi-block per graph ----------------
__global__ void k_bounds(const int* __restrict__ gid, int* __restrict__ start) {
    int n = blockIdx.x * 256 + threadIdx.x;
    if (n < N_NODES) {
        int g = gid[n];
        if (n == 0) {
            for (int x = 0; x <= g; ++x) start[x] = 0;
        } else {
            int pg = gid[n - 1];
            for (int x = pg + 1; x <= g; ++x) start[x] = n;
        }
        if (n == N_NODES - 1) {
            for (int x = g + 1; x <= NGRAPH; ++x) start[x] = N_NODES;
        }
    }
}

__global__ void k_gate2(const float* __restrict__ H, const float* __restrict__ H0,
                        const float* __restrict__ gW, const float* __restrict__ gb,
                        float* __restrict__ gate) {
    int l = threadIdx.x & 63;
    int n = blockIdx.x * 4 + (threadIdx.x >> 6);
    float v = H[(size_t)n * 64 + l] * gW[l] + H0[(size_t)n * 64 + l] * gW[64 + l];
    for (int off = 32; off > 0; off >>= 1) v += __shfl_xor(v, off, 64);
    if (l == 0) gate[n] = v + gb[0];
}

__global__ __launch_bounds__(64) void k_poolA(const float* __restrict__ gate,
                                              const int* __restrict__ start,
                                              float* __restrict__ pmax) {
    int g = blockIdx.x, s = blockIdx.y;
    int beg = start[g], len = start[g + 1] - beg;
    int sb = beg + (int)((long long)len * s / PS);
    int se = beg + (int)((long long)len * (s + 1) / PS);
    float m = -INFINITY;
    for (int n = sb + threadIdx.x; n < se; n += 64) m = fmaxf(m, gate[n]);
    for (int off = 32; off > 0; off >>= 1) m = fmaxf(m, __shfl_xor(m, off, 64));
    if (threadIdx.x == 0) pmax[g * PS + s] = m;
}

__global__ void k_poolB(const float* __restrict__ pmax, float* __restrict__ gm) {
    int g = threadIdx.x;  // 64 threads
    float m = -INFINITY;
    for (int s = 0; s < PS; ++s) m = fmaxf(m, pmax[g * PS + s]);
    if (!isfinite(m)) m = 0.0f;   // reference's empty-graph guard
    gm[g] = m;
}

__global__ __launch_bounds__(256) void k_poolC(const float* __restrict__ H,
                                               const float* __restrict__ H0,
                                               const float* __restrict__ gate,
                                               const int* __restrict__ start,
                                               const float* __restrict__ gm,
                                               float* __restrict__ pnum,
                                               float* __restrict__ pden) {
    int g = blockIdx.x, s = blockIdx.y;
    int beg = start[g], len = start[g + 1] - beg;
    int sb = beg + (int)((long long)len * s / PS);
    int se = beg + (int)((long long)len * (s + 1) / PS);
    int t = threadIdx.x;
    int lane = t & 63, wave = t >> 6;
    float m = gm[g];
    __shared__ float shh[4][64], sh0[4][64], ses[4];
    float ah = 0.f, ah0 = 0.f, es = 0.f;
    for (int n = sb + wave; n < se; n += 4) {
        float e = expf(gate[n] - m);
        es += e;
        ah  += e * H [(size_t)n * 64 + lane];
        ah0 += e * H0[(size_t)n * 64 + lane];
    }
    shh[wave][lane] = ah; sh0[wave][lane] = ah0;
    if (lane == 0) ses[wave] = es;
    __syncthreads();
    if (wave == 0) {
        float r  = shh[0][lane] + shh[1][lane] + shh[2][lane] + shh[3][lane];
        float r0 = sh0[0][lane] + sh0[1][lane] + sh0[2][lane] + sh0[3][lane];
        int base = (g * PS + s) * 128;
        pnum[base + lane]      = r;
        pnum[base + 64 + lane] = r0;
        if (lane == 0) pden[g * PS + s] = ses[0] + ses[1] + ses[2] + ses[3];
    }
}

__global__ __launch_bounds__(128) void k_poolD(const float* __restrict__ pnum,
                                               const float* __restrict__ pden,
                                               float* __restrict__ ro) {
    int g = blockIdx.x;
    int c = threadIdx.x;
    float den = 0.f;
    for (int s = 0; s < PS; ++s) den += pden[g * PS + s];
    float nu = 0.f;
    for (int s = 0; s < PS; ++s) nu += pnum[(g * PS + s) * 128 + c];
    ro[g * 128 + c] = (den > 0.f) ? nu / den : 0.f;
}

__global__ void k_logits(const float* __restrict__ ro, const float* __restrict__ oW,
                         const float* __restrict__ ob, float* __restrict__ out) {
    int t = threadIdx.x;
    int b = t >> 1;
    int c = t & 1;
    float acc = ob[c];
    for (int k = 0; k < 128; ++k) acc = fmaf(ro[b * 128 + k], oW[k * 2 + c], acc);
    out[b * 2 + c] = acc;
}

extern "C" void kernel_launch(void* const* d_in, const int* in_sizes, int n_in,
                              void* d_out, int out_size, void* d_ws, size_t ws_size,
                              hipStream_t stream) {
    (void)in_sizes; (void)n_in; (void)out_size; (void)ws_size;
    const float* ann = (const float*)d_in[0];
    const int* src   = (const int*)d_in[1];
    const int* dst   = (const int*)d_in[2];
    const int* ety   = (const int*)d_in[3];
    const int* gid   = (const int*)d_in[4];
    const float* rW  = (const float*)d_in[5];
    const float* rb  = (const float*)d_in[6];
    const float* eW  = (const float*)d_in[7];
    const float* eb  = (const float*)d_in[8];
    const float* Wi  = (const float*)d_in[9];
    const float* Bi  = (const float*)d_in[10];
    const float* Wh  = (const float*)d_in[11];
    const float* Bh  = (const float*)d_in[12];
    const float* gW  = (const float*)d_in[13];
    const float* gb  = (const float*)d_in[14];
    const float* oW  = (const float*)d_in[15];
    const float* ob  = (const float*)d_in[16];
    float* out = (float*)d_out;

    char* p = (char*)d_ws;
    auto take = [&](size_t nbytes) -> void* {
        void* r = (void*)p;
        p += (nbytes + 255) & ~((size_t)255);
        return r;
    };
    float* h0      = (float*)take((size_t)N_NODES * 64 * 4);
    float* h       = (float*)take((size_t)N_NODES * 64 * 4);
    float* abuf    = (float*)take((size_t)N_NODES * 64 * 4);
    float* buf1    = (float*)take((size_t)N_NODES * 448 * 4);   // [gh(192, j*3+g) | trans(4x64)]
    float* W448    = (float*)take(64 * 448 * 4);
    float* bias448 = (float*)take(448 * 4);
    float* WiA     = (float*)take(64 * 192 * 4);
    float* biA     = (float*)take(192 * 4);
    int* deg       = (int*)take((size_t)N_NODES * 4);
    int* cur       = (int*)take((size_t)N_NODES * 4);
    int* rs        = (int*)take((size_t)(N_NODES + 1) * 4);
    int* part      = (int*)take(512);
    int* colidx    = (int*)take((size_t)N_EDGES * 4);
    float* gate    = (float*)take((size_t)N_NODES * 4);
    int* start     = (int*)take((size_t)(NGRAPH + 1) * 4);
    float* pmax    = (float*)take(NGRAPH * PS * 4);
    float* gm      = (float*)take(NGRAPH * 4);
    float* pnum    = (float*)take((size_t)NGRAPH * PS * 128 * 4);
    float* pden    = (float*)take(NGRAPH * PS * 4);
    float* ro      = (float*)take(NGRAPH * 128 * 4);

    // ---- CSR build (by dst)
    hipMemsetAsync(deg, 0, (size_t)N_NODES * 4, stream);
    hipMemsetAsync(cur, 0, (size_t)N_NODES * 4, stream);
    k_count<<<(N_EDGES + 255) / 256, 256, 0, stream>>>(dst, deg);
    int nb = (N_NODES + 1023) / 1024;  // 98
    k_scan1<<<nb, 256, 0, stream>>>(deg, rs, part);
    k_scan2<<<1, 64, 0, stream>>>(part, rs, nb);
    k_scan3<<<(N_NODES + 255) / 256, 256, 0, stream>>>(rs, part);
    k_fill<<<(N_EDGES + 255) / 256, 256, 0, stream>>>(src, dst, ety, rs, cur, colidx);

    // ---- weight prep + graph bounds
    k_prep2<<<112, 256, 0, stream>>>(Wh, Bh, eW, eb, Wi, Bi, W448, bias448, WiA, biA);
    k_bounds<<<(N_NODES + 255) / 256, 256, 0, stream>>>(gid, start);

    int ntiles = (N_NODES + 127) / 128;  // 782

    // ---- reduce layer: h = h0 = ann @ rW + rb
    k_gemm<<<dim3(1, ntiles), 256, 0, stream>>>(ann, ASIZE, ASIZE, rW, 64, rb, h, h0, 64);

    // ---- message-passing steps (R4-proven trio, aggregate 4-way unrolled)
    for (int s = 0; s < NSTEPS; ++s) {
        k_gemm<<<dim3(7, ntiles), 256, 0, stream>>>(h, 64, 64, W448, 448, bias448,
                                                    buf1, nullptr, 448);
        k_aggregate<<<N_NODES / 4, 256, 0, stream>>>(buf1, rs, colidx, abuf);
        k_gruF<<<(N_NODES + 63) / 64, 256, 0, stream>>>(abuf, WiA, biA, buf1, h);
    }

    // ---- pooling + classifier (atomic-free, multi-block)
    k_gate2<<<N_NODES / 4, 256, 0, stream>>>(h, h0, gW, gb, gate);
    k_poolA<<<dim3(NGRAPH, PS), 64, 0, stream>>>(gate, start, pmax);
    k_poolB<<<1, 64, 0, stream>>>(pmax, gm);
    k_poolC<<<dim3(NGRAPH, PS), 256, 0, stream>>>(h, h0, gate, start, gm, pnum, pden);
    k_poolD<<<NGRAPH, 128, 0, stream>>>(pnum, pden, ro);
    k_logits<<<1, 128, 0, stream>>>(ro, oW, ob, out);
}